// Round 2
// baseline (85.461 us; speedup 1.0000x reference)
//
#include <hip/hip_runtime.h>

#define NROWS 4096
#define NCOLS 10000
#define NLAT  64
#define NCOLG 2500   /* NCOLS / 4 */
#define TPB   256
#define MAXRC 128    /* row chunks: 10 x-blocks * 128 = 1280 blocks = 5/CU exactly */

// Kernel 1: the single streaming pass over X (163.84 MB).
// Thread owns 4 consecutive columns (float4, coalesced); block-row y
// accumulates rowsPerChunk rows; partial colsum + colsum-of-squares go
// to workspace in fixed slots (deterministic).
__global__ void colsum_partials(const float* __restrict__ X,
                                float* __restrict__ ps,
                                float* __restrict__ ps2,
                                int rowsPerChunk) {
    int jg = blockIdx.x * TPB + threadIdx.x;          // column group (4 cols)
    if (jg >= NCOLG) return;
    int r0 = blockIdx.y * rowsPerChunk;
    int r1 = r0 + rowsPerChunk;
    if (r1 > NROWS) r1 = NROWS;

    float s0 = 0.f, s1 = 0.f, s2 = 0.f, s3 = 0.f;
    float q0 = 0.f, q1 = 0.f, q2 = 0.f, q3 = 0.f;
    const float* base = X + (size_t)r0 * NCOLS + (size_t)jg * 4;
    #pragma unroll 4
    for (int r = r0; r < r1; ++r) {
        float4 v = *reinterpret_cast<const float4*>(base);
        base += NCOLS;
        s0 += v.x; s1 += v.y; s2 += v.z; s3 += v.w;
        q0 += v.x * v.x; q1 += v.y * v.y; q2 += v.z * v.z; q3 += v.w * v.w;
    }
    size_t o = (size_t)blockIdx.y * NCOLS + (size_t)jg * 4;
    *reinterpret_cast<float4*>(ps  + o) = make_float4(s0, s1, s2, s3);
    *reinterpret_cast<float4*>(ps2 + o) = make_float4(q0, q1, q2, q3);
}

// Kernel 2: fold chunk partials -> s[j], s2[j]; read V row once per column;
// produce per-block partials of BOTH q = sum_j s2[j]*||V[j,:]||^2 AND
// t[0..63] += s[j]*V[j,:] (the matvec fused in — V row is already in regs).
// All reductions are fixed-order (butterfly + LDS) -> deterministic.
__global__ void fold_q_t(const float* __restrict__ ps,
                         const float* __restrict__ ps2,
                         const float* __restrict__ V,
                         float* __restrict__ tpart,
                         float* __restrict__ qpart,
                         int rc) {
    int j = blockIdx.x * TPB + threadIdx.x;
    float q = 0.f;
    float4 tv[NLAT / 4];
    #pragma unroll
    for (int k = 0; k < NLAT / 4; ++k) tv[k] = make_float4(0.f, 0.f, 0.f, 0.f);

    if (j < NCOLS) {
        float s = 0.f, s2 = 0.f;
        for (int c = 0; c < rc; ++c) {
            s  += ps [(size_t)c * NCOLS + j];
            s2 += ps2[(size_t)c * NCOLS + j];
        }
        float w2 = 0.f;
        const float4* vp = reinterpret_cast<const float4*>(V + (size_t)j * NLAT);
        #pragma unroll
        for (int k = 0; k < NLAT / 4; ++k) {
            float4 v = vp[k];
            w2 += v.x * v.x + v.y * v.y + v.z * v.z + v.w * v.w;
            tv[k].x = s * v.x; tv[k].y = s * v.y;
            tv[k].z = s * v.z; tv[k].w = s * v.w;
        }
        q = s2 * w2;
    }

    // 64-lane butterfly reduce of q and the 64-float t-vector
    #pragma unroll
    for (int st = 1; st < 64; st <<= 1) {
        q += __shfl_xor(q, st, 64);
        #pragma unroll
        for (int k = 0; k < NLAT / 4; ++k) {
            tv[k].x += __shfl_xor(tv[k].x, st, 64);
            tv[k].y += __shfl_xor(tv[k].y, st, 64);
            tv[k].z += __shfl_xor(tv[k].z, st, 64);
            tv[k].w += __shfl_xor(tv[k].w, st, 64);
        }
    }

    __shared__ float lds_t[4][NLAT];
    __shared__ float lds_q[4];
    int lane = threadIdx.x & 63, w = threadIdx.x >> 6;
    if (lane == 0) {
        lds_q[w] = q;
        #pragma unroll
        for (int k = 0; k < NLAT / 4; ++k)
            *reinterpret_cast<float4*>(&lds_t[w][k * 4]) = tv[k];
    }
    __syncthreads();
    if (threadIdx.x < NLAT) {
        float tt = lds_t[0][threadIdx.x] + lds_t[1][threadIdx.x]
                 + lds_t[2][threadIdx.x] + lds_t[3][threadIdx.x];
        tpart[(size_t)blockIdx.x * NLAT + threadIdx.x] = tt;
    }
    if (threadIdx.x == 0)
        qpart[blockIdx.x] = lds_q[0] + lds_q[1] + lds_q[2] + lds_q[3];
}

// Kernel 3: out = 0.5 * (sum_f t[f]^2 - q). One wave, fixed order.
__global__ void finalize(const float* __restrict__ tpart,
                         const float* __restrict__ qpart,
                         int nb, float* __restrict__ out) {
    int f = threadIdx.x;          // 64 threads
    float t = 0.f;
    for (int b = 0; b < nb; ++b) t += tpart[(size_t)b * NLAT + f];
    float tt = t * t;
    #pragma unroll
    for (int st = 1; st < 64; st <<= 1) tt += __shfl_xor(tt, st, 64);
    if (f == 0) {
        float q = 0.f;
        for (int b = 0; b < nb; ++b) q += qpart[b];
        out[0] = 0.5f * (tt - q);
    }
}

extern "C" void kernel_launch(void* const* d_in, const int* in_sizes, int n_in,
                              void* d_out, int out_size, void* d_ws, size_t ws_size,
                              hipStream_t stream) {
    const float* X = (const float*)d_in[0];   // [4096, 10000] f32
    const float* V = (const float*)d_in[1];   // [10000, 64]  f32
    float* out = (float*)d_out;               // scalar f32

    int nqb = (NCOLS + TPB - 1) / TPB;        // 40 fold blocks

    // Choose row-chunk count rc to fit workspace (ws is ~640MB; this is belt
    // and braces): need rc*2*NCOLS + nqb*(NLAT+1) floats.
    size_t floats = ws_size / sizeof(float);
    const size_t overhead = (size_t)nqb * (NLAT + 1) + 64;
    long rc = 1;
    if (floats > overhead + 2 * NCOLS)
        rc = (long)((floats - overhead) / (2 * (size_t)NCOLS));
    if (rc > MAXRC) rc = MAXRC;
    if (rc < 1) rc = 1;
    int rowsPerChunk = (NROWS + (int)rc - 1) / (int)rc;
    int nrc = (NROWS + rowsPerChunk - 1) / rowsPerChunk;   // actual chunks

    float* ps    = (float*)d_ws;                    // [nrc][NCOLS]
    float* ps2   = ps  + (size_t)nrc * NCOLS;       // [nrc][NCOLS]
    float* tpart = ps2 + (size_t)nrc * NCOLS;       // [nqb][NLAT]
    float* qpart = tpart + (size_t)nqb * NLAT;      // [nqb]

    colsum_partials<<<dim3((NCOLG + TPB - 1) / TPB, nrc), TPB, 0, stream>>>(
        X, ps, ps2, rowsPerChunk);
    fold_q_t<<<nqb, TPB, 0, stream>>>(ps, ps2, V, tpart, qpart, nrc);
    finalize<<<1, 64, 0, stream>>>(tpart, qpart, nqb, out);
}

// Round 3
// 51.262 us; speedup vs baseline: 1.6671x; 1.6671x over previous
//
#include <hip/hip_runtime.h>

#define NROWS 4096
#define NCOLS 10000
#define NLAT  64
#define NCOLG 2500      /* NCOLS / 4 */
#define TPB   256
#define NRC   128       /* row chunks in kernel 1 */
#define RPC   32        /* rows per chunk = NROWS / NRC */
#define NSLICE 8        /* chunk slices in kernel 2 */
#define CPS   (NRC / NSLICE)   /* 16 chunks per slice */
#define NCB   40        /* column blocks in kernel 2 */
#define CPB   250       /* columns per block (40*250 = 10000) */
#define NBLK2 (NCB * NSLICE)   /* 320 partials */

// Kernel 1: single streaming pass over X (163.84 MB). Thread owns 4
// consecutive columns (float4 coalesced); block-row y accumulates 32 rows;
// partial colsum + colsum^2 to fixed workspace slots (deterministic).
// Grid (10, 128) = 1280 blocks = 5/CU exactly.
__global__ void colsum_partials(const float* __restrict__ X,
                                float* __restrict__ ps,
                                float* __restrict__ ps2) {
    int jg = blockIdx.x * TPB + threadIdx.x;          // column group (4 cols)
    if (jg >= NCOLG) return;
    int r0 = blockIdx.y * RPC;

    float s0 = 0.f, s1 = 0.f, s2 = 0.f, s3 = 0.f;
    float q0 = 0.f, q1 = 0.f, q2 = 0.f, q3 = 0.f;
    const float* base = X + (size_t)r0 * NCOLS + (size_t)jg * 4;
    #pragma unroll 4
    for (int r = 0; r < RPC; ++r) {
        float4 v = *reinterpret_cast<const float4*>(base);
        base += NCOLS;
        s0 += v.x; s1 += v.y; s2 += v.z; s3 += v.w;
        q0 += v.x * v.x; q1 += v.y * v.y; q2 += v.z * v.z; q3 += v.w * v.w;
    }
    size_t o = (size_t)blockIdx.y * NCOLS + (size_t)jg * 4;
    *reinterpret_cast<float4*>(ps  + o) = make_float4(s0, s1, s2, s3);
    *reinterpret_cast<float4*>(ps2 + o) = make_float4(q0, q1, q2, q3);
}

// Kernel 2: distributed fold + q + t partials. Both q and t distribute over
// row-chunk slices, so block (cb, sl) folds 16 chunks for its 250 columns and
// emits a q-partial and a t[64]-partial. 320 blocks -> 1280 waves (latency
// fix vs the 40-block fold). All reduction orders fixed -> deterministic.
__global__ void fold_q_t(const float* __restrict__ ps,
                         const float* __restrict__ ps2,
                         const float* __restrict__ V,
                         float* __restrict__ tpart,
                         float* __restrict__ qpart) {
    int cb = blockIdx.x;               // 0..39   column block
    int sl = blockIdx.y;               // 0..7    chunk slice
    int j  = threadIdx.x;
    int col = cb * CPB + j;
    bool active = (j < CPB);

    float s = 0.f, s2 = 0.f, q = 0.f;
    if (active) {
        int c0 = sl * CPS;
        #pragma unroll 4
        for (int c = c0; c < c0 + CPS; ++c) {
            s  += ps [(size_t)c * NCOLS + col];
            s2 += ps2[(size_t)c * NCOLS + col];
        }
        float w2 = 0.f;
        const float4* vp = reinterpret_cast<const float4*>(V + (size_t)col * NLAT);
        #pragma unroll
        for (int k = 0; k < NLAT / 4; ++k) {
            float4 v = vp[k];
            w2 += v.x * v.x + v.y * v.y + v.z * v.z + v.w * v.w;
        }
        q = s2 * w2;
    }

    // q: butterfly within wave, LDS across the 4 waves
    #pragma unroll
    for (int st = 1; st < 64; st <<= 1) q += __shfl_xor(q, st, 64);

    __shared__ float lds_q[4];
    __shared__ float lds_s[TPB];
    __shared__ float lds_t[4][NLAT];
    int lane = threadIdx.x & 63, w = threadIdx.x >> 6;
    if (lane == 0) lds_q[w] = q;
    lds_s[j] = active ? s : 0.f;
    __syncthreads();

    // t-partial: lane owns latent f; wave w strides the block's 250 columns.
    // lds_s[c] is a wave-uniform broadcast; V read is 256B coalesced.
    float acc = 0.f;
    const float* Vb = V + (size_t)cb * CPB * NLAT;
    for (int c = w; c < CPB; c += 4)
        acc += lds_s[c] * Vb[(size_t)c * NLAT + lane];
    lds_t[w][lane] = acc;
    __syncthreads();

    int bid = sl * NCB + cb;
    if (threadIdx.x < NLAT)
        tpart[(size_t)bid * NLAT + threadIdx.x] =
            lds_t[0][threadIdx.x] + lds_t[1][threadIdx.x] +
            lds_t[2][threadIdx.x] + lds_t[3][threadIdx.x];
    if (threadIdx.x == 0)
        qpart[bid] = lds_q[0] + lds_q[1] + lds_q[2] + lds_q[3];
}

// Kernel 3: out = 0.5 * (sum_f t[f]^2 - q). One wave, fixed order.
__global__ void finalize(const float* __restrict__ tpart,
                         const float* __restrict__ qpart,
                         float* __restrict__ out) {
    int f = threadIdx.x;               // 64 threads
    float t = 0.f;
    for (int b = 0; b < NBLK2; ++b) t += tpart[(size_t)b * NLAT + f];
    float q = 0.f;
    for (int b = f; b < NBLK2; b += 64) q += qpart[b];
    float tt = t * t;
    #pragma unroll
    for (int st = 1; st < 64; st <<= 1) {
        tt += __shfl_xor(tt, st, 64);
        q  += __shfl_xor(q,  st, 64);
    }
    if (f == 0) out[0] = 0.5f * (tt - q);
}

extern "C" void kernel_launch(void* const* d_in, const int* in_sizes, int n_in,
                              void* d_out, int out_size, void* d_ws, size_t ws_size,
                              hipStream_t stream) {
    const float* X = (const float*)d_in[0];   // [4096, 10000] f32
    const float* V = (const float*)d_in[1];   // [10000, 64]  f32
    float* out = (float*)d_out;               // scalar f32

    float* ps    = (float*)d_ws;                       // [NRC][NCOLS]
    float* ps2   = ps  + (size_t)NRC * NCOLS;          // [NRC][NCOLS]
    float* tpart = ps2 + (size_t)NRC * NCOLS;          // [NBLK2][NLAT]
    float* qpart = tpart + (size_t)NBLK2 * NLAT;       // [NBLK2]

    colsum_partials<<<dim3((NCOLG + TPB - 1) / TPB, NRC), TPB, 0, stream>>>(X, ps, ps2);
    fold_q_t<<<dim3(NCB, NSLICE), TPB, 0, stream>>>(ps, ps2, V, tpart, qpart);
    finalize<<<1, 64, 0, stream>>>(tpart, qpart, out);
}